// Round 1
// baseline (371.545 us; speedup 1.0000x reference)
//
#include <hip/hip_runtime.h>
#include <hip/hip_cooperative_groups.h>
#include <math.h>

namespace cg = cooperative_groups;

// Problem constants (fixed by setup_inputs)
constexpr int B   = 32;
constexpr int C   = 256;
constexpr int F   = 64;        // C/4
constexpr int HW  = 64 * 64;   // 4096
constexpr int HW4 = HW / 4;    // 1024 float4 per (b,c)
constexpr int P4  = B * HW4;   // 32768 float4 positions per f
constexpr float EPSV = 1e-5f;

// Fused cooperative kernel geometry: 1024 blocks = 4 blocks/CU on 256 CUs
constexpr int NBLK    = 1024;
constexpr int SBLOCKS = NBLK / F;               // 16 stats chunks per f
constexpr int SITER   = P4 / (SBLOCKS * 256);   // 8 float4 per thread
constexpr int TCHUNKS = P4 / 256;               // 128 transform chunks per f
constexpr int TTOT    = F * TCHUNKS;            // 8192 transform work units

typedef float f32x4 __attribute__((ext_vector_type(4)));

// ---------------------------------------------------------------------------
// Fused kernel: stats -> grid.sync -> replicated per-block solve -> transform
// ---------------------------------------------------------------------------
__global__ __launch_bounds__(256, 4) void fused_kernel(
    const float* __restrict__ x,
    const float* __restrict__ weight,   // [4,4,F]
    const float* __restrict__ bias,     // [4,F]
    float* __restrict__ out,
    float* __restrict__ sums)           // [F][14], pre-zeroed
{
    const int tid = threadIdx.x;
    const int bid = blockIdx.x;
    const float4* xb = reinterpret_cast<const float4*>(x);

    __shared__ float red[4][14];
    __shared__ float sMc[F][20];

    // ---------------- phase 1: per-f 14-way reduction ----------------
    {
        const int f     = bid >> 4;             // / SBLOCKS
        const int chunk = bid & (SBLOCKS - 1);

        float acc[14];
#pragma unroll
        for (int i = 0; i < 14; ++i) acc[i] = 0.f;

#pragma unroll
        for (int it = 0; it < SITER; ++it) {
            const int p   = chunk * (256 * SITER) + it * 256 + tid; // [0, P4)
            const int b   = p >> 10;            // / HW4
            const int hw4 = p & (HW4 - 1);
            float4 v[4];
#pragma unroll
            for (int q = 0; q < 4; ++q)
                v[q] = xb[(size_t)(b * C + q * F + f) * HW4 + hw4];
#pragma unroll
            for (int l = 0; l < 4; ++l) {
                float e0 = ((const float*)&v[0])[l];
                float e1 = ((const float*)&v[1])[l];
                float e2 = ((const float*)&v[2])[l];
                float e3 = ((const float*)&v[3])[l];
                acc[0] += e0; acc[1] += e1; acc[2] += e2; acc[3] += e3;
                acc[4]  += e0 * e0; acc[5]  += e0 * e1; acc[6]  += e0 * e2; acc[7]  += e0 * e3;
                acc[8]  += e1 * e1; acc[9]  += e1 * e2; acc[10] += e1 * e3;
                acc[11] += e2 * e2; acc[12] += e2 * e3;
                acc[13] += e3 * e3;
            }
        }

        // 64-lane wave shuffle reduction
#pragma unroll
        for (int i = 0; i < 14; ++i) {
#pragma unroll
            for (int off = 32; off >= 1; off >>= 1)
                acc[i] += __shfl_down(acc[i], off, 64);
        }

        const int wave = tid >> 6;
        const int lane = tid & 63;
        if (lane == 0) {
#pragma unroll
            for (int i = 0; i < 14; ++i) red[wave][i] = acc[i];
        }
        __syncthreads();
        if (tid < 14) {
            float t = red[0][tid] + red[1][tid] + red[2][tid] + red[3][tid];
            atomicAdd(&sums[f * 14 + tid], t);   // device-scope RMW
        }
    }

    cg::this_grid().sync();

    // ---------------- phase 2: per-f solve, replicated per block (into LDS) --
    if (tid < F) {
        const int f = tid;
        const float invN = 1.0f / (float)(B * HW);

        float s14[14];
#pragma unroll
        for (int i = 0; i < 14; ++i)
            s14[i] = __hip_atomic_load(&sums[f * 14 + i], __ATOMIC_RELAXED,
                                       __HIP_MEMORY_SCOPE_AGENT);

        float m[4];
#pragma unroll
        for (int q = 0; q < 4; ++q) m[q] = s14[q] * invN;

        float cov[4][4];
        {
            int k = 4;
            for (int i = 0; i < 4; ++i)
                for (int j = i; j < 4; ++j) {
                    float cij = s14[k] * invN - m[i] * m[j];
                    cov[i][j] = cij;
                    cov[j][i] = cij;
                    ++k;
                }
        }
#pragma unroll
        for (int i = 0; i < 4; ++i) cov[i][i] += EPSV;

        // Cholesky (lower)
        float L[4][4] = {};
        for (int i = 0; i < 4; ++i) {
            for (int j = 0; j <= i; ++j) {
                float s = cov[i][j];
                for (int k = 0; k < j; ++k) s -= L[i][k] * L[j][k];
                if (i == j) L[i][j] = sqrtf(s);
                else        L[i][j] = s / L[j][j];
            }
        }
        // invert lower-triangular L
        float Li[4][4] = {};
        for (int j = 0; j < 4; ++j) {
            Li[j][j] = 1.0f / L[j][j];
            for (int i = j + 1; i < 4; ++i) {
                float s = 0.f;
                for (int k = j; k < i; ++k) s += L[i][k] * Li[k][j];
                Li[i][j] = -s / L[i][i];
            }
        }
        // M = W_f * Li,  c = bias_f - M * m
        float M[4][4];
        for (int i = 0; i < 4; ++i)
            for (int j = 0; j < 4; ++j) {
                float s = 0.f;
                for (int k = 0; k < 4; ++k)
                    s += weight[(i * 4 + k) * F + f] * Li[k][j];
                M[i][j] = s;
            }
        for (int i = 0; i < 4; ++i) {
            float ci = bias[i * F + f];
            for (int j = 0; j < 4; ++j) ci -= M[i][j] * m[j];
#pragma unroll
            for (int j = 0; j < 4; ++j) sMc[f][i * 4 + j] = M[i][j];
            sMc[f][16 + i] = ci;
        }
    }
    __syncthreads();

    // ---------------- phase 3: out = M*x + c (nontemporal stores) ------------
    f32x4* ob = reinterpret_cast<f32x4*>(out);
    for (int c = bid; c < TTOT; c += NBLK) {
        const int f   = c >> 7;                 // / TCHUNKS
        const int p   = ((c & (TCHUNKS - 1)) << 8) + tid;
        const int b   = p >> 10;
        const int hw4 = p & (HW4 - 1);

        float4 v[4];
#pragma unroll
        for (int q = 0; q < 4; ++q)
            v[q] = xb[(size_t)(b * C + q * F + f) * HW4 + hw4];

#pragma unroll
        for (int i = 0; i < 4; ++i) {
            const float m0 = sMc[f][i * 4 + 0], m1 = sMc[f][i * 4 + 1],
                        m2 = sMc[f][i * 4 + 2], m3 = sMc[f][i * 4 + 3];
            const float ci = sMc[f][16 + i];
            f32x4 o;
            o.x = ci + m0 * v[0].x + m1 * v[1].x + m2 * v[2].x + m3 * v[3].x;
            o.y = ci + m0 * v[0].y + m1 * v[1].y + m2 * v[2].y + m3 * v[3].y;
            o.z = ci + m0 * v[0].z + m1 * v[1].z + m2 * v[2].z + m3 * v[3].z;
            o.w = ci + m0 * v[0].w + m1 * v[1].w + m2 * v[2].w + m3 * v[3].w;
            __builtin_nontemporal_store(o, &ob[(size_t)(b * C + i * F + f) * HW4 + hw4]);
        }
    }
}

// ---------------------------------------------------------------------------
// Fallback path (proven 3-kernel version) in case cooperative launch fails
// ---------------------------------------------------------------------------
constexpr int FB_SBLOCKS = 32;
constexpr int FB_SITER   = P4 / (FB_SBLOCKS * 256);
constexpr int FB_TBLOCKS = P4 / 256;

__global__ __launch_bounds__(256) void stats_kernel(const float* __restrict__ x,
                                                    float* __restrict__ sums) {
    const int f     = blockIdx.x / FB_SBLOCKS;
    const int chunk = blockIdx.x % FB_SBLOCKS;
    const int tid   = threadIdx.x;

    float acc[14];
#pragma unroll
    for (int i = 0; i < 14; ++i) acc[i] = 0.f;

    const float4* xb = reinterpret_cast<const float4*>(x);

#pragma unroll
    for (int it = 0; it < FB_SITER; ++it) {
        const int p   = chunk * (256 * FB_SITER) + it * 256 + tid;
        const int b   = p >> 10;
        const int hw4 = p & (HW4 - 1);
        float4 v[4];
#pragma unroll
        for (int q = 0; q < 4; ++q)
            v[q] = xb[(size_t)(b * C + q * F + f) * HW4 + hw4];
#pragma unroll
        for (int l = 0; l < 4; ++l) {
            float e0 = ((const float*)&v[0])[l];
            float e1 = ((const float*)&v[1])[l];
            float e2 = ((const float*)&v[2])[l];
            float e3 = ((const float*)&v[3])[l];
            acc[0] += e0; acc[1] += e1; acc[2] += e2; acc[3] += e3;
            acc[4]  += e0 * e0; acc[5]  += e0 * e1; acc[6]  += e0 * e2; acc[7]  += e0 * e3;
            acc[8]  += e1 * e1; acc[9]  += e1 * e2; acc[10] += e1 * e3;
            acc[11] += e2 * e2; acc[12] += e2 * e3;
            acc[13] += e3 * e3;
        }
    }

#pragma unroll
    for (int i = 0; i < 14; ++i) {
#pragma unroll
        for (int off = 32; off >= 1; off >>= 1)
            acc[i] += __shfl_down(acc[i], off, 64);
    }

    __shared__ float red[4][14];
    const int wave = tid >> 6;
    const int lane = tid & 63;
    if (lane == 0) {
#pragma unroll
        for (int i = 0; i < 14; ++i) red[wave][i] = acc[i];
    }
    __syncthreads();
    if (tid < 14) {
        float t = red[0][tid] + red[1][tid] + red[2][tid] + red[3][tid];
        atomicAdd(&sums[f * 14 + tid], t);
    }
}

__global__ __launch_bounds__(64) void solve_kernel(const float* __restrict__ sums,
                                                   const float* __restrict__ weight,
                                                   const float* __restrict__ bias,
                                                   float* __restrict__ Mc) {
    const int f = threadIdx.x;
    if (f >= F) return;
    const float invN = 1.0f / (float)(B * HW);

    float m[4];
#pragma unroll
    for (int q = 0; q < 4; ++q) m[q] = sums[f * 14 + q] * invN;

    float cov[4][4];
    {
        int k = 4;
        for (int i = 0; i < 4; ++i)
            for (int j = i; j < 4; ++j) {
                float cij = sums[f * 14 + k] * invN - m[i] * m[j];
                cov[i][j] = cij;
                cov[j][i] = cij;
                ++k;
            }
    }
#pragma unroll
    for (int i = 0; i < 4; ++i) cov[i][i] += EPSV;

    float L[4][4] = {};
    for (int i = 0; i < 4; ++i) {
        for (int j = 0; j <= i; ++j) {
            float s = cov[i][j];
            for (int k = 0; k < j; ++k) s -= L[i][k] * L[j][k];
            if (i == j) L[i][j] = sqrtf(s);
            else        L[i][j] = s / L[j][j];
        }
    }
    float Li[4][4] = {};
    for (int j = 0; j < 4; ++j) {
        Li[j][j] = 1.0f / L[j][j];
        for (int i = j + 1; i < 4; ++i) {
            float s = 0.f;
            for (int k = j; k < i; ++k) s += L[i][k] * Li[k][j];
            Li[i][j] = -s / L[i][i];
        }
    }
    float M[4][4];
    for (int i = 0; i < 4; ++i)
        for (int j = 0; j < 4; ++j) {
            float s = 0.f;
            for (int k = 0; k < 4; ++k)
                s += weight[(i * 4 + k) * F + f] * Li[k][j];
            M[i][j] = s;
        }
    for (int i = 0; i < 4; ++i) {
        float ci = bias[i * F + f];
        for (int j = 0; j < 4; ++j) ci -= M[i][j] * m[j];
#pragma unroll
        for (int j = 0; j < 4; ++j) Mc[f * 20 + i * 4 + j] = M[i][j];
        Mc[f * 20 + 16 + i] = ci;
    }
}

__global__ __launch_bounds__(256) void transform_kernel(const float* __restrict__ x,
                                                        const float* __restrict__ Mc,
                                                        float* __restrict__ out) {
    const int f     = blockIdx.x / FB_TBLOCKS;
    const int chunk = blockIdx.x % FB_TBLOCKS;

    __shared__ float sM[20];
    if (threadIdx.x < 20) sM[threadIdx.x] = Mc[f * 20 + threadIdx.x];
    __syncthreads();

    const int p   = chunk * 256 + threadIdx.x;
    const int b   = p >> 10;
    const int hw4 = p & (HW4 - 1);

    const float4* xb = reinterpret_cast<const float4*>(x);
    float4*       ob = reinterpret_cast<float4*>(out);

    float4 v[4];
#pragma unroll
    for (int q = 0; q < 4; ++q)
        v[q] = xb[(size_t)(b * C + q * F + f) * HW4 + hw4];

#pragma unroll
    for (int i = 0; i < 4; ++i) {
        const float m0 = sM[i * 4 + 0], m1 = sM[i * 4 + 1],
                    m2 = sM[i * 4 + 2], m3 = sM[i * 4 + 3];
        const float ci = sM[16 + i];
        float4 o;
        o.x = ci + m0 * v[0].x + m1 * v[1].x + m2 * v[2].x + m3 * v[3].x;
        o.y = ci + m0 * v[0].y + m1 * v[1].y + m2 * v[2].y + m3 * v[3].y;
        o.z = ci + m0 * v[0].z + m1 * v[1].z + m2 * v[2].z + m3 * v[3].z;
        o.w = ci + m0 * v[0].w + m1 * v[1].w + m2 * v[2].w + m3 * v[3].w;
        ob[(size_t)(b * C + i * F + f) * HW4 + hw4] = o;
    }
}

// ---------------------------------------------------------------------------
extern "C" void kernel_launch(void* const* d_in, const int* in_sizes, int n_in,
                              void* d_out, int out_size, void* d_ws, size_t ws_size,
                              hipStream_t stream) {
    const float* x      = (const float*)d_in[0];
    const float* weight = (const float*)d_in[1];
    const float* bias   = (const float*)d_in[2];
    float*       out    = (float*)d_out;

    float* sums = (float*)d_ws;          // F*14 floats
    float* Mc   = sums + F * 14;         // F*20 floats (fallback path only)

    hipMemsetAsync(sums, 0, F * 14 * sizeof(float), stream);

    void* args[] = {(void*)&x, (void*)&weight, (void*)&bias, (void*)&out, (void*)&sums};
    hipError_t err = hipLaunchCooperativeKernel((void*)fused_kernel,
                                                dim3(NBLK), dim3(256),
                                                args, 0, stream);
    if (err != hipSuccess) {
        // Proven 3-kernel fallback
        stats_kernel<<<F * FB_SBLOCKS, 256, 0, stream>>>(x, sums);
        solve_kernel<<<1, 64, 0, stream>>>(sums, weight, bias, Mc);
        transform_kernel<<<F * FB_TBLOCKS, 256, 0, stream>>>(x, Mc, out);
    }
}

// Round 3
// 353.089 us; speedup vs baseline: 1.0523x; 1.0523x over previous
//
#include <hip/hip_runtime.h>
#include <math.h>

// Problem constants (fixed by setup_inputs)
constexpr int B   = 32;
constexpr int C   = 256;
constexpr int F   = 64;        // C/4
constexpr int HW  = 64 * 64;   // 4096
constexpr int HW4 = HW / 4;    // 1024 float4 per (b,c)
constexpr int P4  = B * HW4;   // 32768 float4 positions per f
constexpr float EPSV = 1e-5f;

constexpr int SBLOCKS = 32;                   // stats chunks per f
constexpr int SITER   = P4 / (SBLOCKS * 256); // 4 float4 per thread
constexpr int NSTAT   = F * SBLOCKS;          // 2048 stats blocks
constexpr int TBLOCKS = P4 / 256;             // 128 transform blocks per f

typedef float f32x4 __attribute__((ext_vector_type(4)));

// ---------------------------------------------------------------------------
// Kernel 1: per-f 14-way reduction; LAST block also does all 64 4x4 solves.
// (no spin-wait: every block exits unconditionally; the last arrival at the
//  atomic counter is elected to run the 64-thread solve epilogue)
// ---------------------------------------------------------------------------
__global__ __launch_bounds__(256) void stats_solve_kernel(
    const float* __restrict__ x,
    const float* __restrict__ weight,   // [4,4,F]
    const float* __restrict__ bias,     // [4,F]
    float* __restrict__ sums,           // [F][14], pre-zeroed
    unsigned int* __restrict__ cnt,     // pre-zeroed
    float* __restrict__ Mc)             // [F][20] output
{
    const int f     = blockIdx.x / SBLOCKS;
    const int chunk = blockIdx.x % SBLOCKS;
    const int tid   = threadIdx.x;

    float acc[14];
#pragma unroll
    for (int i = 0; i < 14; ++i) acc[i] = 0.f;

    const float4* xb = reinterpret_cast<const float4*>(x);

#pragma unroll
    for (int it = 0; it < SITER; ++it) {
        const int p   = chunk * (256 * SITER) + it * 256 + tid; // [0, P4)
        const int b   = p >> 10;        // / HW4
        const int hw4 = p & (HW4 - 1);
        float4 v[4];
#pragma unroll
        for (int q = 0; q < 4; ++q)
            v[q] = xb[(size_t)(b * C + q * F + f) * HW4 + hw4];
#pragma unroll
        for (int l = 0; l < 4; ++l) {
            float e0 = ((const float*)&v[0])[l];
            float e1 = ((const float*)&v[1])[l];
            float e2 = ((const float*)&v[2])[l];
            float e3 = ((const float*)&v[3])[l];
            acc[0] += e0; acc[1] += e1; acc[2] += e2; acc[3] += e3;
            acc[4]  += e0 * e0; acc[5]  += e0 * e1; acc[6]  += e0 * e2; acc[7]  += e0 * e3;
            acc[8]  += e1 * e1; acc[9]  += e1 * e2; acc[10] += e1 * e3;
            acc[11] += e2 * e2; acc[12] += e2 * e3;
            acc[13] += e3 * e3;
        }
    }

    // 64-lane wave shuffle reduction
#pragma unroll
    for (int i = 0; i < 14; ++i) {
#pragma unroll
        for (int off = 32; off >= 1; off >>= 1)
            acc[i] += __shfl_down(acc[i], off, 64);
    }

    __shared__ float red[4][14];
    __shared__ bool  s_last;
    const int wave = tid >> 6;
    const int lane = tid & 63;
    if (lane == 0) {
#pragma unroll
        for (int i = 0; i < 14; ++i) red[wave][i] = acc[i];
    }
    __syncthreads();
    if (tid < 14) {
        float t = red[0][tid] + red[1][tid] + red[2][tid] + red[3][tid];
        atomicAdd(&sums[f * 14 + tid], t);   // device-scope RMW (G12)
    }
    __syncthreads();

    // ---- last-block-done election ----
    if (tid == 0) {
        __threadfence();                       // release our sums updates
        unsigned int old = atomicAdd(cnt, 1u);
        s_last = (old == (unsigned)(NSTAT - 1));
    }
    __syncthreads();
    if (!s_last) return;

    __threadfence();                           // acquire side
    if (tid < F) {
        const int ff = tid;
        const float invN = 1.0f / (float)(B * HW);

        float s14[14];
#pragma unroll
        for (int i = 0; i < 14; ++i)
            s14[i] = __hip_atomic_load(&sums[ff * 14 + i], __ATOMIC_RELAXED,
                                       __HIP_MEMORY_SCOPE_AGENT);

        float m[4];
#pragma unroll
        for (int q = 0; q < 4; ++q) m[q] = s14[q] * invN;

        float cov[4][4];
        {
            int k = 4;
            for (int i = 0; i < 4; ++i)
                for (int j = i; j < 4; ++j) {
                    float cij = s14[k] * invN - m[i] * m[j];
                    cov[i][j] = cij;
                    cov[j][i] = cij;
                    ++k;
                }
        }
#pragma unroll
        for (int i = 0; i < 4; ++i) cov[i][i] += EPSV;

        // Cholesky (lower)
        float L[4][4] = {};
        for (int i = 0; i < 4; ++i) {
            for (int j = 0; j <= i; ++j) {
                float s = cov[i][j];
                for (int k = 0; k < j; ++k) s -= L[i][k] * L[j][k];
                if (i == j) L[i][j] = sqrtf(s);
                else        L[i][j] = s / L[j][j];
            }
        }
        // invert lower-triangular L
        float Li[4][4] = {};
        for (int j = 0; j < 4; ++j) {
            Li[j][j] = 1.0f / L[j][j];
            for (int i = j + 1; i < 4; ++i) {
                float s = 0.f;
                for (int k = j; k < i; ++k) s += L[i][k] * Li[k][j];
                Li[i][j] = -s / L[i][i];
            }
        }
        // M = W_f * Li,  c = bias_f - M * m
        float M[4][4];
        for (int i = 0; i < 4; ++i)
            for (int j = 0; j < 4; ++j) {
                float s = 0.f;
                for (int k = 0; k < 4; ++k)
                    s += weight[(i * 4 + k) * F + ff] * Li[k][j];
                M[i][j] = s;
            }
        for (int i = 0; i < 4; ++i) {
            float ci = bias[i * F + ff];
            for (int j = 0; j < 4; ++j) ci -= M[i][j] * m[j];
#pragma unroll
            for (int j = 0; j < 4; ++j) Mc[ff * 20 + i * 4 + j] = M[i][j];
            Mc[ff * 20 + 16 + i] = ci;
        }
        // plain stores: kernel completion flushes them; next dispatch sees Mc
    }
}

// ---------------------------------------------------------------------------
// Kernel 2: out = M*x + c. Block-uniform Mc -> scalar loads, no LDS/barrier.
// Nontemporal stores keep x resident in L3 for the read stream.
// ---------------------------------------------------------------------------
__global__ __launch_bounds__(256) void transform_kernel(
    const float* __restrict__ x,
    const float* __restrict__ Mc,
    float* __restrict__ out)
{
    const int f     = blockIdx.x >> 7;           // / TBLOCKS
    const int chunk = blockIdx.x & (TBLOCKS - 1);

    // block-uniform -> compiler emits scalar loads (L2 broadcast)
    const float* mc = Mc + f * 20;
    float mm[20];
#pragma unroll
    for (int i = 0; i < 20; ++i) mm[i] = mc[i];

    const int p   = chunk * 256 + threadIdx.x;   // [0, P4)
    const int b   = p >> 10;
    const int hw4 = p & (HW4 - 1);

    const float4* xb = reinterpret_cast<const float4*>(x);
    f32x4*        ob = reinterpret_cast<f32x4*>(out);

    float4 v[4];
#pragma unroll
    for (int q = 0; q < 4; ++q)
        v[q] = xb[(size_t)(b * C + q * F + f) * HW4 + hw4];

#pragma unroll
    for (int i = 0; i < 4; ++i) {
        const float m0 = mm[i * 4 + 0], m1 = mm[i * 4 + 1],
                    m2 = mm[i * 4 + 2], m3 = mm[i * 4 + 3];
        const float ci = mm[16 + i];
        f32x4 o;
        o.x = ci + m0 * v[0].x + m1 * v[1].x + m2 * v[2].x + m3 * v[3].x;
        o.y = ci + m0 * v[0].y + m1 * v[1].y + m2 * v[2].y + m3 * v[3].y;
        o.z = ci + m0 * v[0].z + m1 * v[1].z + m2 * v[2].z + m3 * v[3].z;
        o.w = ci + m0 * v[0].w + m1 * v[1].w + m2 * v[2].w + m3 * v[3].w;
        __builtin_nontemporal_store(o, &ob[(size_t)(b * C + i * F + f) * HW4 + hw4]);
    }
}

// ---------------------------------------------------------------------------
extern "C" void kernel_launch(void* const* d_in, const int* in_sizes, int n_in,
                              void* d_out, int out_size, void* d_ws, size_t ws_size,
                              hipStream_t stream) {
    const float* x      = (const float*)d_in[0];
    const float* weight = (const float*)d_in[1];
    const float* bias   = (const float*)d_in[2];
    float*       out    = (float*)d_out;

    float*        sums = (float*)d_ws;                 // F*14 floats
    unsigned int* cnt  = (unsigned int*)(sums + F*14); // 1 uint (16-float slot)
    float*        Mc   = sums + F * 14 + 16;           // F*20 floats

    // zero sums + counter in one memset
    hipMemsetAsync(sums, 0, (F * 14 + 16) * sizeof(float), stream);

    stats_solve_kernel<<<NSTAT, 256, 0, stream>>>(x, weight, bias, sums, cnt, Mc);
    transform_kernel<<<F * TBLOCKS, 256, 0, stream>>>(x, Mc, out);
}

// Round 6
// 254.743 us; speedup vs baseline: 1.4585x; 1.3861x over previous
//
#include <hip/hip_runtime.h>
#include <math.h>

// Problem constants (fixed by setup_inputs)
constexpr int B   = 32;
constexpr int C   = 256;
constexpr int F   = 64;        // C/4
constexpr int HW  = 64 * 64;   // 4096
constexpr int HW4 = HW / 4;    // 1024 float4 per (b,c)
constexpr int P4  = B * HW4;   // 32768 float4 positions per f
constexpr float EPSV = 1e-5f;

constexpr int SBLOCKS = 32;                   // stats chunks per f
constexpr int SITER   = P4 / (SBLOCKS * 256); // 4 float4 per thread
constexpr int TBLOCKS = P4 / 256;             // 128 transform blocks per f

typedef float f32x4 __attribute__((ext_vector_type(4)));

// ---------------------------------------------------------------------------
// Kernel 1: per-f 14-way reduction (4 sums + 10 products). Round-0 proven.
// No fences, no epilogue — dispatch boundary provides coherence.
// ---------------------------------------------------------------------------
__global__ __launch_bounds__(256) void stats_kernel(const float* __restrict__ x,
                                                    float* __restrict__ sums) {
    const int f     = blockIdx.x / SBLOCKS;
    const int chunk = blockIdx.x % SBLOCKS;
    const int tid   = threadIdx.x;

    float acc[14];
#pragma unroll
    for (int i = 0; i < 14; ++i) acc[i] = 0.f;

    const float4* xb = reinterpret_cast<const float4*>(x);

#pragma unroll
    for (int it = 0; it < SITER; ++it) {
        const int p   = chunk * (256 * SITER) + it * 256 + tid; // [0, P4)
        const int b   = p >> 10;        // / HW4
        const int hw4 = p & (HW4 - 1);
        float4 v[4];
#pragma unroll
        for (int q = 0; q < 4; ++q)
            v[q] = xb[(size_t)(b * C + q * F + f) * HW4 + hw4];
#pragma unroll
        for (int l = 0; l < 4; ++l) {
            float e0 = ((const float*)&v[0])[l];
            float e1 = ((const float*)&v[1])[l];
            float e2 = ((const float*)&v[2])[l];
            float e3 = ((const float*)&v[3])[l];
            acc[0] += e0; acc[1] += e1; acc[2] += e2; acc[3] += e3;
            acc[4]  += e0 * e0; acc[5]  += e0 * e1; acc[6]  += e0 * e2; acc[7]  += e0 * e3;
            acc[8]  += e1 * e1; acc[9]  += e1 * e2; acc[10] += e1 * e3;
            acc[11] += e2 * e2; acc[12] += e2 * e3;
            acc[13] += e3 * e3;
        }
    }

    // wave (64-lane) shuffle reduction
#pragma unroll
    for (int i = 0; i < 14; ++i) {
#pragma unroll
        for (int off = 32; off >= 1; off >>= 1)
            acc[i] += __shfl_down(acc[i], off, 64);
    }

    __shared__ float red[4][14];
    const int wave = tid >> 6;
    const int lane = tid & 63;
    if (lane == 0) {
#pragma unroll
        for (int i = 0; i < 14; ++i) red[wave][i] = acc[i];
    }
    __syncthreads();
    if (tid < 14) {
        float t = red[0][tid] + red[1][tid] + red[2][tid] + red[3][tid];
        atomicAdd(&sums[f * 14 + tid], t);   // device-scope RMW (G12)
    }
}

// ---------------------------------------------------------------------------
// Kernel 2: per-block inline solve (redundant across threads, block-uniform,
// no LDS/barrier) + out = M*x + c with nontemporal stores.
// x loads are issued BEFORE the solve so HBM latency hides under the VALU.
// ---------------------------------------------------------------------------
__global__ __launch_bounds__(256) void transform_kernel(
    const float* __restrict__ x,
    const float* __restrict__ sums,     // [F][14]
    const float* __restrict__ weight,   // [4,4,F]
    const float* __restrict__ bias,     // [4,F]
    float* __restrict__ out)
{
    const int f     = blockIdx.x >> 7;           // / TBLOCKS
    const int chunk = blockIdx.x & (TBLOCKS - 1);

    const int p   = chunk * 256 + threadIdx.x;   // [0, P4)
    const int b   = p >> 10;
    const int hw4 = p & (HW4 - 1);

    const float4* xb = reinterpret_cast<const float4*>(x);
    f32x4*        ob = reinterpret_cast<f32x4*>(out);

    // ---- issue x loads first (in flight during the solve) ----
    float4 v[4];
#pragma unroll
    for (int q = 0; q < 4; ++q)
        v[q] = xb[(size_t)(b * C + q * F + f) * HW4 + hw4];

    // ---- redundant per-thread solve (all inputs block-uniform) ----
    const float invN = 1.0f / (float)(B * HW);

    float s14[14];
#pragma unroll
    for (int i = 0; i < 14; ++i) s14[i] = sums[f * 14 + i];

    float m[4];
#pragma unroll
    for (int q = 0; q < 4; ++q) m[q] = s14[q] * invN;

    float cov[4][4];
    {
        int k = 4;
#pragma unroll
        for (int i = 0; i < 4; ++i)
#pragma unroll
            for (int j = i; j < 4; ++j) {
                float cij = s14[k] * invN - m[i] * m[j];
                cov[i][j] = cij;
                cov[j][i] = cij;
                ++k;
            }
    }
#pragma unroll
    for (int i = 0; i < 4; ++i) cov[i][i] += EPSV;

    // Cholesky (lower) — same op order as the original solve kernel
    float L[4][4] = {};
#pragma unroll
    for (int i = 0; i < 4; ++i) {
#pragma unroll
        for (int j = 0; j <= i; ++j) {
            float s = cov[i][j];
#pragma unroll
            for (int k = 0; k < j; ++k) s -= L[i][k] * L[j][k];
            if (i == j) L[i][j] = sqrtf(s);
            else        L[i][j] = s / L[j][j];
        }
    }
    // invert lower-triangular L
    float Li[4][4] = {};
#pragma unroll
    for (int j = 0; j < 4; ++j) {
        Li[j][j] = 1.0f / L[j][j];
#pragma unroll
        for (int i = j + 1; i < 4; ++i) {
            float s = 0.f;
#pragma unroll
            for (int k = j; k < i; ++k) s += L[i][k] * Li[k][j];
            Li[i][j] = -s / L[i][i];
        }
    }
    // M = W_f * Li,  c = bias_f - M * m
    float M[4][4];
#pragma unroll
    for (int i = 0; i < 4; ++i)
#pragma unroll
        for (int j = 0; j < 4; ++j) {
            float s = 0.f;
#pragma unroll
            for (int k = 0; k < 4; ++k)
                s += weight[(i * 4 + k) * F + f] * Li[k][j];
            M[i][j] = s;
        }
    float cvec[4];
#pragma unroll
    for (int i = 0; i < 4; ++i) {
        float ci = bias[i * F + f];
#pragma unroll
        for (int j = 0; j < 4; ++j) ci -= M[i][j] * m[j];
        cvec[i] = ci;
    }

    // ---- apply: out = M*v + c (nontemporal: keep x resident in L3) ----
#pragma unroll
    for (int i = 0; i < 4; ++i) {
        const float m0 = M[i][0], m1 = M[i][1], m2 = M[i][2], m3 = M[i][3];
        const float ci = cvec[i];
        f32x4 o;
        o.x = ci + m0 * v[0].x + m1 * v[1].x + m2 * v[2].x + m3 * v[3].x;
        o.y = ci + m0 * v[0].y + m1 * v[1].y + m2 * v[2].y + m3 * v[3].y;
        o.z = ci + m0 * v[0].z + m1 * v[1].z + m2 * v[2].z + m3 * v[3].z;
        o.w = ci + m0 * v[0].w + m1 * v[1].w + m2 * v[2].w + m3 * v[3].w;
        __builtin_nontemporal_store(o, &ob[(size_t)(b * C + i * F + f) * HW4 + hw4]);
    }
}

// ---------------------------------------------------------------------------
extern "C" void kernel_launch(void* const* d_in, const int* in_sizes, int n_in,
                              void* d_out, int out_size, void* d_ws, size_t ws_size,
                              hipStream_t stream) {
    const float* x      = (const float*)d_in[0];
    const float* weight = (const float*)d_in[1];
    const float* bias   = (const float*)d_in[2];
    float*       out    = (float*)d_out;

    float* sums = (float*)d_ws;          // F*14 floats

    hipMemsetAsync(sums, 0, F * 14 * sizeof(float), stream);
    stats_kernel<<<F * SBLOCKS, 256, 0, stream>>>(x, sums);
    transform_kernel<<<F * TBLOCKS, 256, 0, stream>>>(x, sums, weight, bias, out);
}

// Round 7
// 253.007 us; speedup vs baseline: 1.4685x; 1.0069x over previous
//
#include <hip/hip_runtime.h>
#include <math.h>

// Problem constants (fixed by setup_inputs)
constexpr int B   = 32;
constexpr int C   = 256;
constexpr int F   = 64;        // C/4
constexpr int HW  = 64 * 64;   // 4096
constexpr int HW4 = HW / 4;    // 1024 float4 per (b,c)
constexpr int P4  = B * HW4;   // 32768 float4 positions per f
constexpr float EPSV = 1e-5f;

constexpr int SBLOCKS = 32;                   // stats chunks per f
constexpr int SITER   = P4 / (SBLOCKS * 256); // 4 float4 per thread
constexpr int TBLK    = 32;                   // transform chunks per f
constexpr int TITER   = P4 / (TBLK * 256);    // 4 float4-positions per thread

typedef float f32x4 __attribute__((ext_vector_type(4)));

// ---------------------------------------------------------------------------
// Kernel 1: per-f 14-way reduction -> non-overlapping partial slots.
// Plain stores (each slot written exactly once): no memset, no atomics.
// ---------------------------------------------------------------------------
__global__ __launch_bounds__(256) void stats_kernel(const float* __restrict__ x,
                                                    float* __restrict__ partial) {
    const int f     = blockIdx.x / SBLOCKS;
    const int chunk = blockIdx.x % SBLOCKS;
    const int tid   = threadIdx.x;

    float acc[14];
#pragma unroll
    for (int i = 0; i < 14; ++i) acc[i] = 0.f;

    const float4* xb = reinterpret_cast<const float4*>(x);

#pragma unroll
    for (int it = 0; it < SITER; ++it) {
        const int p   = chunk * (256 * SITER) + it * 256 + tid; // [0, P4)
        const int b   = p >> 10;        // / HW4
        const int hw4 = p & (HW4 - 1);
        float4 v[4];
#pragma unroll
        for (int q = 0; q < 4; ++q)
            v[q] = xb[(size_t)(b * C + q * F + f) * HW4 + hw4];
#pragma unroll
        for (int l = 0; l < 4; ++l) {
            float e0 = ((const float*)&v[0])[l];
            float e1 = ((const float*)&v[1])[l];
            float e2 = ((const float*)&v[2])[l];
            float e3 = ((const float*)&v[3])[l];
            acc[0] += e0; acc[1] += e1; acc[2] += e2; acc[3] += e3;
            acc[4]  += e0 * e0; acc[5]  += e0 * e1; acc[6]  += e0 * e2; acc[7]  += e0 * e3;
            acc[8]  += e1 * e1; acc[9]  += e1 * e2; acc[10] += e1 * e3;
            acc[11] += e2 * e2; acc[12] += e2 * e3;
            acc[13] += e3 * e3;
        }
    }

    // wave (64-lane) shuffle reduction
#pragma unroll
    for (int i = 0; i < 14; ++i) {
#pragma unroll
        for (int off = 32; off >= 1; off >>= 1)
            acc[i] += __shfl_down(acc[i], off, 64);
    }

    __shared__ float red[4][14];
    const int wave = tid >> 6;
    const int lane = tid & 63;
    if (lane == 0) {
#pragma unroll
        for (int i = 0; i < 14; ++i) red[wave][i] = acc[i];
    }
    __syncthreads();
    if (tid < 14) {
        float t = red[0][tid] + red[1][tid] + red[2][tid] + red[3][tid];
        partial[(size_t)(f * SBLOCKS + chunk) * 14 + tid] = t;  // plain store
    }
}

// ---------------------------------------------------------------------------
// Shared device helper: solve M (4x4) and c (4) from the 14 sums.
// Same op order as the original solve kernel -> bitwise-identical results.
// ---------------------------------------------------------------------------
__device__ __forceinline__ void solve_from_sums(
    const float* __restrict__ s14, int f,
    const float* __restrict__ weight, const float* __restrict__ bias,
    float M[4][4], float cvec[4])
{
    const float invN = 1.0f / (float)(B * HW);

    float m[4];
#pragma unroll
    for (int q = 0; q < 4; ++q) m[q] = s14[q] * invN;

    float cov[4][4];
    {
        int k = 4;
#pragma unroll
        for (int i = 0; i < 4; ++i)
#pragma unroll
            for (int j = i; j < 4; ++j) {
                float cij = s14[k] * invN - m[i] * m[j];
                cov[i][j] = cij;
                cov[j][i] = cij;
                ++k;
            }
    }
#pragma unroll
    for (int i = 0; i < 4; ++i) cov[i][i] += EPSV;

    float L[4][4] = {};
#pragma unroll
    for (int i = 0; i < 4; ++i) {
#pragma unroll
        for (int j = 0; j <= i; ++j) {
            float s = cov[i][j];
#pragma unroll
            for (int k = 0; k < j; ++k) s -= L[i][k] * L[j][k];
            if (i == j) L[i][j] = sqrtf(s);
            else        L[i][j] = s / L[j][j];
        }
    }
    float Li[4][4] = {};
#pragma unroll
    for (int j = 0; j < 4; ++j) {
        Li[j][j] = 1.0f / L[j][j];
#pragma unroll
        for (int i = j + 1; i < 4; ++i) {
            float s = 0.f;
#pragma unroll
            for (int k = j; k < i; ++k) s += L[i][k] * Li[k][j];
            Li[i][j] = -s / L[i][i];
        }
    }
#pragma unroll
    for (int i = 0; i < 4; ++i)
#pragma unroll
        for (int j = 0; j < 4; ++j) {
            float s = 0.f;
#pragma unroll
            for (int k = 0; k < 4; ++k)
                s += weight[(i * 4 + k) * F + f] * Li[k][j];
            M[i][j] = s;
        }
#pragma unroll
    for (int i = 0; i < 4; ++i) {
        float ci = bias[i * F + f];
#pragma unroll
        for (int j = 0; j < 4; ++j) ci -= M[i][j] * m[j];
        cvec[i] = ci;
    }
}

// ---------------------------------------------------------------------------
// Kernel 2: pre-reduce partials (14 threads) -> LDS -> one solve per block
// (amortized over 4 positions/thread) -> pipelined apply with nt stores.
// ---------------------------------------------------------------------------
__global__ __launch_bounds__(256) void transform_kernel(
    const float* __restrict__ x,
    const float* __restrict__ partial,  // [F*SBLOCKS][14]
    const float* __restrict__ weight,   // [4,4,F]
    const float* __restrict__ bias,     // [4,F]
    float* __restrict__ out)
{
    const int f     = blockIdx.x >> 5;           // / TBLK
    const int chunk = blockIdx.x & (TBLK - 1);
    const int tid   = threadIdx.x;
    const int b     = chunk;                     // this block owns one batch image

    const float4* xb = reinterpret_cast<const float4*>(x);
    f32x4*        ob = reinterpret_cast<f32x4*>(out);

    size_t plane[4];
#pragma unroll
    for (int q = 0; q < 4; ++q)
        plane[q] = (size_t)(b * C + q * F + f) * HW4;

    // ---- prefetch sub-tile 0 (in flight during reduce + solve) ----
    float4 va[4], vb[4];
#pragma unroll
    for (int q = 0; q < 4; ++q) va[q] = xb[plane[q] + tid];

    // ---- 14-thread pre-reduction of the 32 partials into LDS ----
    __shared__ float s14[14];
    if (tid < 14) {
        const float* pp = partial + (size_t)f * SBLOCKS * 14 + tid;
        float s = 0.f;
#pragma unroll
        for (int c = 0; c < SBLOCKS; ++c) s += pp[c * 14];
        s14[tid] = s;
    }
    __syncthreads();

    // ---- one redundant solve per thread, amortized over TITER positions ----
    float M[4][4], cvec[4];
    float s14r[14];
#pragma unroll
    for (int i = 0; i < 14; ++i) s14r[i] = s14[i];
    solve_from_sums(s14r, f, weight, bias, M, cvec);

    // ---- software-pipelined apply over 4 sub-tiles (static indexing) ----
#define APPLY(V, IT)                                                          \
    {                                                                         \
        const int hw4 = (IT) * 256 + tid;                                     \
        _Pragma("unroll")                                                     \
        for (int i = 0; i < 4; ++i) {                                         \
            const float m0 = M[i][0], m1 = M[i][1], m2 = M[i][2], m3 = M[i][3]; \
            const float ci = cvec[i];                                         \
            f32x4 o;                                                          \
            o.x = ci + m0 * V[0].x + m1 * V[1].x + m2 * V[2].x + m3 * V[3].x; \
            o.y = ci + m0 * V[0].y + m1 * V[1].y + m2 * V[2].y + m3 * V[3].y; \
            o.z = ci + m0 * V[0].z + m1 * V[1].z + m2 * V[2].z + m3 * V[3].z; \
            o.w = ci + m0 * V[0].w + m1 * V[1].w + m2 * V[2].w + m3 * V[3].w; \
            __builtin_nontemporal_store(o, &ob[plane[i] + hw4]);              \
        }                                                                     \
    }

#pragma unroll
    for (int q = 0; q < 4; ++q) vb[q] = xb[plane[q] + 256 + tid];   // prefetch 1
    APPLY(va, 0);
#pragma unroll
    for (int q = 0; q < 4; ++q) va[q] = xb[plane[q] + 512 + tid];   // prefetch 2
    APPLY(vb, 1);
#pragma unroll
    for (int q = 0; q < 4; ++q) vb[q] = xb[plane[q] + 768 + tid];   // prefetch 3
    APPLY(va, 2);
    APPLY(vb, 3);
#undef APPLY
}

// ---------------------------------------------------------------------------
// Fallback (exact round-6 path) if workspace can't hold the partial buffer.
// ---------------------------------------------------------------------------
__global__ __launch_bounds__(256) void stats_atomic_kernel(const float* __restrict__ x,
                                                           float* __restrict__ sums) {
    const int f     = blockIdx.x / SBLOCKS;
    const int chunk = blockIdx.x % SBLOCKS;
    const int tid   = threadIdx.x;

    float acc[14];
#pragma unroll
    for (int i = 0; i < 14; ++i) acc[i] = 0.f;

    const float4* xb = reinterpret_cast<const float4*>(x);

#pragma unroll
    for (int it = 0; it < SITER; ++it) {
        const int p   = chunk * (256 * SITER) + it * 256 + tid;
        const int b   = p >> 10;
        const int hw4 = p & (HW4 - 1);
        float4 v[4];
#pragma unroll
        for (int q = 0; q < 4; ++q)
            v[q] = xb[(size_t)(b * C + q * F + f) * HW4 + hw4];
#pragma unroll
        for (int l = 0; l < 4; ++l) {
            float e0 = ((const float*)&v[0])[l];
            float e1 = ((const float*)&v[1])[l];
            float e2 = ((const float*)&v[2])[l];
            float e3 = ((const float*)&v[3])[l];
            acc[0] += e0; acc[1] += e1; acc[2] += e2; acc[3] += e3;
            acc[4]  += e0 * e0; acc[5]  += e0 * e1; acc[6]  += e0 * e2; acc[7]  += e0 * e3;
            acc[8]  += e1 * e1; acc[9]  += e1 * e2; acc[10] += e1 * e3;
            acc[11] += e2 * e2; acc[12] += e2 * e3;
            acc[13] += e3 * e3;
        }
    }
#pragma unroll
    for (int i = 0; i < 14; ++i) {
#pragma unroll
        for (int off = 32; off >= 1; off >>= 1)
            acc[i] += __shfl_down(acc[i], off, 64);
    }
    __shared__ float red[4][14];
    const int wave = tid >> 6;
    const int lane = tid & 63;
    if (lane == 0) {
#pragma unroll
        for (int i = 0; i < 14; ++i) red[wave][i] = acc[i];
    }
    __syncthreads();
    if (tid < 14) {
        float t = red[0][tid] + red[1][tid] + red[2][tid] + red[3][tid];
        atomicAdd(&sums[f * 14 + tid], t);
    }
}

__global__ __launch_bounds__(256) void transform1_kernel(
    const float* __restrict__ x,
    const float* __restrict__ sums,
    const float* __restrict__ weight,
    const float* __restrict__ bias,
    float* __restrict__ out)
{
    const int f     = blockIdx.x >> 7;
    const int chunk = blockIdx.x & 127;
    const int p     = chunk * 256 + threadIdx.x;
    const int b     = p >> 10;
    const int hw4   = p & (HW4 - 1);

    const float4* xb = reinterpret_cast<const float4*>(x);
    f32x4*        ob = reinterpret_cast<f32x4*>(out);

    float4 v[4];
#pragma unroll
    for (int q = 0; q < 4; ++q)
        v[q] = xb[(size_t)(b * C + q * F + f) * HW4 + hw4];

    float s14[14];
#pragma unroll
    for (int i = 0; i < 14; ++i) s14[i] = sums[f * 14 + i];

    float M[4][4], cvec[4];
    solve_from_sums(s14, f, weight, bias, M, cvec);

#pragma unroll
    for (int i = 0; i < 4; ++i) {
        const float m0 = M[i][0], m1 = M[i][1], m2 = M[i][2], m3 = M[i][3];
        const float ci = cvec[i];
        f32x4 o;
        o.x = ci + m0 * v[0].x + m1 * v[1].x + m2 * v[2].x + m3 * v[3].x;
        o.y = ci + m0 * v[0].y + m1 * v[1].y + m2 * v[2].y + m3 * v[3].y;
        o.z = ci + m0 * v[0].z + m1 * v[1].z + m2 * v[2].z + m3 * v[3].z;
        o.w = ci + m0 * v[0].w + m1 * v[1].w + m2 * v[2].w + m3 * v[3].w;
        __builtin_nontemporal_store(o, &ob[(size_t)(b * C + i * F + f) * HW4 + hw4]);
    }
}

// ---------------------------------------------------------------------------
extern "C" void kernel_launch(void* const* d_in, const int* in_sizes, int n_in,
                              void* d_out, int out_size, void* d_ws, size_t ws_size,
                              hipStream_t stream) {
    const float* x      = (const float*)d_in[0];
    const float* weight = (const float*)d_in[1];
    const float* bias   = (const float*)d_in[2];
    float*       out    = (float*)d_out;

    const size_t need = (size_t)F * SBLOCKS * 14 * sizeof(float);  // 114688 B
    if (ws_size >= need) {
        float* partial = (float*)d_ws;
        stats_kernel<<<F * SBLOCKS, 256, 0, stream>>>(x, partial);
        transform_kernel<<<F * TBLK, 256, 0, stream>>>(x, partial, weight, bias, out);
    } else {
        // round-6 proven fallback
        float* sums = (float*)d_ws;      // F*14 floats
        hipMemsetAsync(sums, 0, F * 14 * sizeof(float), stream);
        stats_atomic_kernel<<<F * SBLOCKS, 256, 0, stream>>>(x, sums);
        transform1_kernel<<<F * 128, 256, 0, stream>>>(x, sums, weight, bias, out);
    }
}

// Round 9
// 250.381 us; speedup vs baseline: 1.4839x; 1.0105x over previous
//
#include <hip/hip_runtime.h>
#include <math.h>

// Problem constants (fixed by setup_inputs)
constexpr int B   = 32;
constexpr int C   = 256;
constexpr int F   = 64;        // C/4
constexpr int HW  = 64 * 64;   // 4096
constexpr int HW4 = HW / 4;    // 1024 float4 per (b,c)
constexpr int P4  = B * HW4;   // 32768 float4 positions per f
constexpr float EPSV = 1e-5f;

constexpr int SBLOCKS = 32;                   // stats chunks per f
constexpr int SITER   = P4 / (SBLOCKS * 256); // 4 float4 per thread
constexpr int TBLK    = 32;                   // transform chunks per f (1 per batch img)

typedef float f32x4 __attribute__((ext_vector_type(4)));

// ---------------------------------------------------------------------------
// Kernel 1: per-f 14-way reduction -> non-overlapping partial slots.
// Plain stores (each slot written exactly once): no memset, no atomics.
// UNCHANGED from round 7 (proven).
// ---------------------------------------------------------------------------
__global__ __launch_bounds__(256) void stats_kernel(const float* __restrict__ x,
                                                    float* __restrict__ partial) {
    const int f     = blockIdx.x / SBLOCKS;
    const int chunk = blockIdx.x % SBLOCKS;
    const int tid   = threadIdx.x;

    float acc[14];
#pragma unroll
    for (int i = 0; i < 14; ++i) acc[i] = 0.f;

    const float4* xb = reinterpret_cast<const float4*>(x);

#pragma unroll
    for (int it = 0; it < SITER; ++it) {
        const int p   = chunk * (256 * SITER) + it * 256 + tid; // [0, P4)
        const int b   = p >> 10;        // / HW4
        const int hw4 = p & (HW4 - 1);
        float4 v[4];
#pragma unroll
        for (int q = 0; q < 4; ++q)
            v[q] = xb[(size_t)(b * C + q * F + f) * HW4 + hw4];
#pragma unroll
        for (int l = 0; l < 4; ++l) {
            float e0 = ((const float*)&v[0])[l];
            float e1 = ((const float*)&v[1])[l];
            float e2 = ((const float*)&v[2])[l];
            float e3 = ((const float*)&v[3])[l];
            acc[0] += e0; acc[1] += e1; acc[2] += e2; acc[3] += e3;
            acc[4]  += e0 * e0; acc[5]  += e0 * e1; acc[6]  += e0 * e2; acc[7]  += e0 * e3;
            acc[8]  += e1 * e1; acc[9]  += e1 * e2; acc[10] += e1 * e3;
            acc[11] += e2 * e2; acc[12] += e2 * e3;
            acc[13] += e3 * e3;
        }
    }

    // wave (64-lane) shuffle reduction
#pragma unroll
    for (int i = 0; i < 14; ++i) {
#pragma unroll
        for (int off = 32; off >= 1; off >>= 1)
            acc[i] += __shfl_down(acc[i], off, 64);
    }

    __shared__ float red[4][14];
    const int wave = tid >> 6;
    const int lane = tid & 63;
    if (lane == 0) {
#pragma unroll
        for (int i = 0; i < 14; ++i) red[wave][i] = acc[i];
    }
    __syncthreads();
    if (tid < 14) {
        float t = red[0][tid] + red[1][tid] + red[2][tid] + red[3][tid];
        partial[(size_t)(f * SBLOCKS + chunk) * 14 + tid] = t;  // plain store
    }
}

// ---------------------------------------------------------------------------
// Shared device helper: solve M (4x4) and c (4) from the 14 sums.
// Same op order as the original solve kernel -> identical numerics.
// ---------------------------------------------------------------------------
__device__ __forceinline__ void solve_from_sums(
    const float* __restrict__ s14, int f,
    const float* __restrict__ weight, const float* __restrict__ bias,
    float M[4][4], float cvec[4])
{
    const float invN = 1.0f / (float)(B * HW);

    float m[4];
#pragma unroll
    for (int q = 0; q < 4; ++q) m[q] = s14[q] * invN;

    float cov[4][4];
    {
        int k = 4;
#pragma unroll
        for (int i = 0; i < 4; ++i)
#pragma unroll
            for (int j = i; j < 4; ++j) {
                float cij = s14[k] * invN - m[i] * m[j];
                cov[i][j] = cij;
                cov[j][i] = cij;
                ++k;
            }
    }
#pragma unroll
    for (int i = 0; i < 4; ++i) cov[i][i] += EPSV;

    float L[4][4] = {};
#pragma unroll
    for (int i = 0; i < 4; ++i) {
#pragma unroll
        for (int j = 0; j <= i; ++j) {
            float s = cov[i][j];
#pragma unroll
            for (int k = 0; k < j; ++k) s -= L[i][k] * L[j][k];
            if (i == j) L[i][j] = sqrtf(s);
            else        L[i][j] = s / L[j][j];
        }
    }
    float Li[4][4] = {};
#pragma unroll
    for (int j = 0; j < 4; ++j) {
        Li[j][j] = 1.0f / L[j][j];
#pragma unroll
        for (int i = j + 1; i < 4; ++i) {
            float s = 0.f;
#pragma unroll
            for (int k = j; k < i; ++k) s += L[i][k] * Li[k][j];
            Li[i][j] = -s / L[i][i];
        }
    }
#pragma unroll
    for (int i = 0; i < 4; ++i)
#pragma unroll
        for (int j = 0; j < 4; ++j) {
            float s = 0.f;
#pragma unroll
            for (int k = 0; k < 4; ++k)
                s += weight[(i * 4 + k) * F + f] * Li[k][j];
            M[i][j] = s;
        }
#pragma unroll
    for (int i = 0; i < 4; ++i) {
        float ci = bias[i * F + f];
#pragma unroll
        for (int j = 0; j < 4; ++j) ci -= M[i][j] * m[j];
        cvec[i] = ci;
    }
}

// ---------------------------------------------------------------------------
// Kernel 2: deep-pipelined transform.
//   pf(t0,t1) -> reduce+solve (hides them) -> pf(t2) -> APPLY0 -> pf(t3)
//   -> APPLY1 -> APPLY2 -> APPLY3.
// nt loads via ext_vector f32x4 (builtin rejects HIP_vector_type float4*).
// nt stores so out doesn't evict x from L3. Static indexing (rule #20).
// ---------------------------------------------------------------------------
__global__ __launch_bounds__(256) void transform_kernel(
    const float* __restrict__ x,
    const float* __restrict__ partial,  // [F*SBLOCKS][14]
    const float* __restrict__ weight,   // [4,4,F]
    const float* __restrict__ bias,     // [4,F]
    float* __restrict__ out)
{
    const int f   = blockIdx.x >> 5;           // / TBLK
    const int b   = blockIdx.x & (TBLK - 1);   // batch image
    const int tid = threadIdx.x;

    const f32x4* xbv = reinterpret_cast<const f32x4*>(x);
    f32x4*       ob  = reinterpret_cast<f32x4*>(out);

    size_t plane[4];
#pragma unroll
    for (int q = 0; q < 4; ++q)
        plane[q] = (size_t)(b * C + q * F + f) * HW4;

    // ---- prefetch sub-tiles 0 and 1 (8 loads in flight during solve) ----
    f32x4 v0[4], v1[4], v2[4], v3[4];
#pragma unroll
    for (int q = 0; q < 4; ++q)
        v0[q] = __builtin_nontemporal_load(&xbv[plane[q] + tid]);
#pragma unroll
    for (int q = 0; q < 4; ++q)
        v1[q] = __builtin_nontemporal_load(&xbv[plane[q] + 256 + tid]);

    // ---- 14-thread pre-reduction of the 32 partials into LDS ----
    __shared__ float s14[14];
    if (tid < 14) {
        const float* pp = partial + (size_t)f * SBLOCKS * 14 + tid;
        float s = 0.f;
#pragma unroll
        for (int c = 0; c < SBLOCKS; ++c) s += pp[c * 14];
        s14[tid] = s;
    }
    __syncthreads();

    // ---- one redundant solve per thread (block-uniform inputs) ----
    float M[4][4], cvec[4];
    float s14r[14];
#pragma unroll
    for (int i = 0; i < 14; ++i) s14r[i] = s14[i];
    solve_from_sums(s14r, f, weight, bias, M, cvec);

#define APPLY(V, IT)                                                          \
    {                                                                         \
        const int hw4 = (IT) * 256 + tid;                                     \
        _Pragma("unroll")                                                     \
        for (int i = 0; i < 4; ++i) {                                         \
            const float m0 = M[i][0], m1 = M[i][1], m2 = M[i][2], m3 = M[i][3]; \
            const float ci = cvec[i];                                         \
            f32x4 o;                                                          \
            o.x = ci + m0 * V[0].x + m1 * V[1].x + m2 * V[2].x + m3 * V[3].x; \
            o.y = ci + m0 * V[0].y + m1 * V[1].y + m2 * V[2].y + m3 * V[3].y; \
            o.z = ci + m0 * V[0].z + m1 * V[1].z + m2 * V[2].z + m3 * V[3].z; \
            o.w = ci + m0 * V[0].w + m1 * V[1].w + m2 * V[2].w + m3 * V[3].w; \
            __builtin_nontemporal_store(o, &ob[plane[i] + hw4]);              \
        }                                                                     \
    }

#pragma unroll
    for (int q = 0; q < 4; ++q)
        v2[q] = __builtin_nontemporal_load(&xbv[plane[q] + 512 + tid]);
    APPLY(v0, 0);
#pragma unroll
    for (int q = 0; q < 4; ++q)
        v3[q] = __builtin_nontemporal_load(&xbv[plane[q] + 768 + tid]);
    APPLY(v1, 1);
    APPLY(v2, 2);
    APPLY(v3, 3);
#undef APPLY
}

// ---------------------------------------------------------------------------
// Fallback (round-6 proven path) if workspace can't hold the partial buffer.
// ---------------------------------------------------------------------------
__global__ __launch_bounds__(256) void stats_atomic_kernel(const float* __restrict__ x,
                                                           float* __restrict__ sums) {
    const int f     = blockIdx.x / SBLOCKS;
    const int chunk = blockIdx.x % SBLOCKS;
    const int tid   = threadIdx.x;

    float acc[14];
#pragma unroll
    for (int i = 0; i < 14; ++i) acc[i] = 0.f;

    const float4* xb = reinterpret_cast<const float4*>(x);

#pragma unroll
    for (int it = 0; it < SITER; ++it) {
        const int p   = chunk * (256 * SITER) + it * 256 + tid;
        const int b   = p >> 10;
        const int hw4 = p & (HW4 - 1);
        float4 v[4];
#pragma unroll
        for (int q = 0; q < 4; ++q)
            v[q] = xb[(size_t)(b * C + q * F + f) * HW4 + hw4];
#pragma unroll
        for (int l = 0; l < 4; ++l) {
            float e0 = ((const float*)&v[0])[l];
            float e1 = ((const float*)&v[1])[l];
            float e2 = ((const float*)&v[2])[l];
            float e3 = ((const float*)&v[3])[l];
            acc[0] += e0; acc[1] += e1; acc[2] += e2; acc[3] += e3;
            acc[4]  += e0 * e0; acc[5]  += e0 * e1; acc[6]  += e0 * e2; acc[7]  += e0 * e3;
            acc[8]  += e1 * e1; acc[9]  += e1 * e2; acc[10] += e1 * e3;
            acc[11] += e2 * e2; acc[12] += e2 * e3;
            acc[13] += e3 * e3;
        }
    }
#pragma unroll
    for (int i = 0; i < 14; ++i) {
#pragma unroll
        for (int off = 32; off >= 1; off >>= 1)
            acc[i] += __shfl_down(acc[i], off, 64);
    }
    __shared__ float red[4][14];
    const int wave = tid >> 6;
    const int lane = tid & 63;
    if (lane == 0) {
#pragma unroll
        for (int i = 0; i < 14; ++i) red[wave][i] = acc[i];
    }
    __syncthreads();
    if (tid < 14) {
        float t = red[0][tid] + red[1][tid] + red[2][tid] + red[3][tid];
        atomicAdd(&sums[f * 14 + tid], t);
    }
}

__global__ __launch_bounds__(256) void transform1_kernel(
    const float* __restrict__ x,
    const float* __restrict__ sums,
    const float* __restrict__ weight,
    const float* __restrict__ bias,
    float* __restrict__ out)
{
    const int f     = blockIdx.x >> 7;
    const int chunk = blockIdx.x & 127;
    const int p     = chunk * 256 + threadIdx.x;
    const int b     = p >> 10;
    const int hw4   = p & (HW4 - 1);

    const float4* xb = reinterpret_cast<const float4*>(x);
    f32x4*        ob = reinterpret_cast<f32x4*>(out);

    float4 v[4];
#pragma unroll
    for (int q = 0; q < 4; ++q)
        v[q] = xb[(size_t)(b * C + q * F + f) * HW4 + hw4];

    float s14[14];
#pragma unroll
    for (int i = 0; i < 14; ++i) s14[i] = sums[f * 14 + i];

    float M[4][4], cvec[4];
    solve_from_sums(s14, f, weight, bias, M, cvec);

#pragma unroll
    for (int i = 0; i < 4; ++i) {
        const float m0 = M[i][0], m1 = M[i][1], m2 = M[i][2], m3 = M[i][3];
        const float ci = cvec[i];
        f32x4 o;
        o.x = ci + m0 * v[0].x + m1 * v[1].x + m2 * v[2].x + m3 * v[3].x;
        o.y = ci + m0 * v[0].y + m1 * v[1].y + m2 * v[2].y + m3 * v[3].y;
        o.z = ci + m0 * v[0].z + m1 * v[1].z + m2 * v[2].z + m3 * v[3].z;
        o.w = ci + m0 * v[0].w + m1 * v[1].w + m2 * v[2].w + m3 * v[3].w;
        __builtin_nontemporal_store(o, &ob[(size_t)(b * C + i * F + f) * HW4 + hw4]);
    }
}

// ---------------------------------------------------------------------------
extern "C" void kernel_launch(void* const* d_in, const int* in_sizes, int n_in,
                              void* d_out, int out_size, void* d_ws, size_t ws_size,
                              hipStream_t stream) {
    const float* x      = (const float*)d_in[0];
    const float* weight = (const float*)d_in[1];
    const float* bias   = (const float*)d_in[2];
    float*       out    = (float*)d_out;

    const size_t need = (size_t)F * SBLOCKS * 14 * sizeof(float);  // 114688 B
    if (ws_size >= need) {
        float* partial = (float*)d_ws;
        stats_kernel<<<F * SBLOCKS, 256, 0, stream>>>(x, partial);
        transform_kernel<<<F * TBLK, 256, 0, stream>>>(x, partial, weight, bias, out);
    } else {
        // round-6 proven fallback
        float* sums = (float*)d_ws;      // F*14 floats
        (void)hipMemsetAsync(sums, 0, F * 14 * sizeof(float), stream);
        stats_atomic_kernel<<<F * SBLOCKS, 256, 0, stream>>>(x, sums);
        transform1_kernel<<<F * 128, 256, 0, stream>>>(x, sums, weight, bias, out);
    }
}